// Round 8
// baseline (131.353 us; speedup 1.0000x reference)
//
#include <hip/hip_runtime.h>
#include <hip/hip_bf16.h>

// ContrastiveLoss: N=8192, D=256, NUM_IDS=1000, MARGIN=0.3
// R8: 256^2-tile GEMM (4x less L2 traffic), 8 waves (2Mx4N), BK=64, 2-buf
// counted-vmcnt pipeline, label-free epilogue (R7 algebra):
//   loss*N = sum_all negv(s) + sum_{same-label ordered pairs} [posv-negv]
// Term 2 via coalesced wave-per-pair kernel (fixes R7's divergent-load sin).

#define MARGINF 0.3f

typedef __attribute__((ext_vector_type(8))) short short8x;    // 8 bf16 (4 VGPRs)
typedef __attribute__((ext_vector_type(16))) float f32x16;    // 16 fp32 acc

// ---------- round-to-nearest-even f32 -> bf16 bits ----------
__device__ __forceinline__ unsigned short f2bf(float f) {
    unsigned int u = __float_as_uint(f);
    unsigned int r = (u + 0x7fffu + ((u >> 16) & 1u)) >> 16;
    return (unsigned short)r;
}
__device__ __forceinline__ float bf2f(unsigned short u) {
    return __uint_as_float(((unsigned int)u) << 16);
}

// ---------- pass 1: fp32 -> bf16 row-major convert (verified R1/R2/R6) ----------
__global__ void __launch_bounds__(256) convert_k(const float* __restrict__ x,
                                                 unsigned short* __restrict__ xb) {
    int i = blockIdx.x * 256 + threadIdx.x;          // 0 .. 262143
    const float4* p = reinterpret_cast<const float4*>(x) + (size_t)i * 2;
    float4 a = p[0];
    float4 b = p[1];
    short8x o;
    o[0] = (short)f2bf(a.x); o[1] = (short)f2bf(a.y);
    o[2] = (short)f2bf(a.z); o[3] = (short)f2bf(a.w);
    o[4] = (short)f2bf(b.x); o[5] = (short)f2bf(b.y);
    o[6] = (short)f2bf(b.z); o[7] = (short)f2bf(b.w);
    reinterpret_cast<short8x*>(xb)[i] = o;
}

// ---------- pass 2: 256^2 pipelined LDS GEMM + label-free neg-sum ----------
// 8 waves (wr=wid>>2 in {0,1}: 128 rows; wc=wid&3: 64 cols), per wave 4x2
// frags of 32x32x16. LDS: 2 bufs x (A 256x128B + B 256x128B) = 128KB.
// Swizzle (verified R1/R2): LDS[row][c'] = global[row][c' ^ (row&7)], 16B chunks.
__global__ void __launch_bounds__(512, 2) gemm_loss_k(const unsigned short* __restrict__ xb,
                                                      double* __restrict__ partials) {
    // XCD-chunked swizzle (528 = 8*66, bijective)
    const int praw = blockIdx.x;
    const int p = (praw & 7) * 66 + (praw >> 3);
    // ---- 1D upper-triangle decode on 32x32 tile grid: p -> (bi <= bj) ----
    int bi = (int)(32.5f - sqrtf(32.5f * 32.5f - 2.0f * (float)p));
    if (bi < 0) bi = 0;
    if (bi > 31) bi = 31;
    while (bi > 0 && (bi * (65 - bi)) / 2 > p) --bi;
    while (((bi + 1) * (64 - bi)) / 2 <= p) ++bi;
    const int bj = bi + (p - (bi * (65 - bi)) / 2);

    __shared__ __align__(16) char ldsb[2 * 65536];   // 128 KB
    __shared__ float redbuf[8];

    const int tid  = threadIdx.x;
    const int lane = tid & 63;
    const int wid  = tid >> 6;       // 0..7
    const int wr   = wid >> 2;       // 0..1 -> 128-row half
    const int wc   = wid & 3;        // 0..3 -> 64-col quarter

    const char* aBase = (const char*)(xb + (size_t)bi * 256 * 256);
    const char* bBase = (const char*)(xb + (size_t)bj * 256 * 256);

    // ---- stage addressing: issue covers 64 rows (512 thr x 16B = 8KB) ----
    // thread t: local row = t>>3, stored chunk c' = t&7;
    // source chunk = c' ^ (row&7)  (row&7 == (t>>3)&7 since issue*64 ≡ 0 mod 8)
    const int srow   = tid >> 3;                       // 0..63
    const int schunk = ((tid & 7) ^ (srow & 7)) << 4;  // source byte offset in row

    // ---- ds_read addressing ----
    const int l31 = lane & 31;
    const int hi  = lane >> 5;       // 0..1 (k-half of 32B k-slab)
    const int s7  = l31 & 7;
    int rA[4], rB[2], xc[4];
#pragma unroll
    for (int fm = 0; fm < 4; ++fm) rA[fm] = (wr * 128 + fm * 32 + l31) * 128;
#pragma unroll
    for (int fn = 0; fn < 2; ++fn) rB[fn] = 65536 / 2 + (wc * 64 + fn * 32 + l31) * 128;
#pragma unroll
    for (int ks = 0; ks < 4; ++ks) xc[ks] = (((2 * ks + hi) ^ s7) << 4);

    f32x16 acc[4][2] = {};

#define STAGE_KT(BUF, T) do {                                                         \
    _Pragma("unroll")                                                                 \
    for (int is_ = 0; is_ < 4; ++is_) {                                               \
        const size_t gr_ = (size_t)(is_ * 64 + srow);                                 \
        const char* sa_ = aBase + gr_ * 512 + (T) * 128 + schunk;                     \
        const char* sb_ = bBase + gr_ * 512 + (T) * 128 + schunk;                     \
        __builtin_amdgcn_global_load_lds(                                             \
            (const __attribute__((address_space(1))) unsigned int*)sa_,               \
            (__attribute__((address_space(3))) unsigned int*)(ldsb + (BUF) * 65536 + is_ * 8192 + tid * 16), \
            16, 0, 0);                                                                \
        __builtin_amdgcn_global_load_lds(                                             \
            (const __attribute__((address_space(1))) unsigned int*)sb_,               \
            (__attribute__((address_space(3))) unsigned int*)(ldsb + (BUF) * 65536 + 32768 + is_ * 8192 + tid * 16), \
            16, 0, 0);                                                                \
    }                                                                                 \
} while (0)

#define GEMM_ITER(T, BUF, VMSTR, DOSTAGE) do {                                        \
    asm volatile("s_waitcnt vmcnt(" VMSTR ")" ::: "memory");                          \
    __builtin_amdgcn_s_barrier();               /* KT T resident in BUF */            \
    const char* lb_ = ldsb + (BUF) * 65536;                                           \
    _Pragma("unroll")                                                                 \
    for (int ks = 0; ks < 3; ++ks) {                                                  \
        short8x af[4], bf[2];                                                         \
        _Pragma("unroll")                                                             \
        for (int fm = 0; fm < 4; ++fm) af[fm] = *(const short8x*)(lb_ + rA[fm] + xc[ks]); \
        _Pragma("unroll")                                                             \
        for (int fn = 0; fn < 2; ++fn) bf[fn] = *(const short8x*)(lb_ + rB[fn] + xc[ks]); \
        _Pragma("unroll")                                                             \
        for (int fm = 0; fm < 4; ++fm)                                                \
            _Pragma("unroll")                                                         \
            for (int fn = 0; fn < 2; ++fn)                                            \
                acc[fm][fn] = __builtin_amdgcn_mfma_f32_32x32x16_bf16(af[fm], bf[fn], acc[fm][fn], 0, 0, 0); \
    }                                                                                 \
    short8x af3[4], bf3[2];                                                           \
    _Pragma("unroll")                                                                 \
    for (int fm = 0; fm < 4; ++fm) af3[fm] = *(const short8x*)(lb_ + rA[fm] + xc[3]); \
    _Pragma("unroll")                                                                 \
    for (int fn = 0; fn < 2; ++fn) bf3[fn] = *(const short8x*)(lb_ + rB[fn] + xc[3]); \
    asm volatile("s_waitcnt lgkmcnt(0)" ::: "memory");                                \
    __builtin_amdgcn_sched_barrier(0);                                                \
    __builtin_amdgcn_s_barrier();               /* all waves done reading BUF */      \
    if (DOSTAGE) STAGE_KT(BUF, (T) + 2);        /* refill freed buffer */             \
    __builtin_amdgcn_s_setprio(1);                                                    \
    _Pragma("unroll")                                                                 \
    for (int fm = 0; fm < 4; ++fm)                                                    \
        _Pragma("unroll")                                                             \
        for (int fn = 0; fn < 2; ++fn)                                                \
            acc[fm][fn] = __builtin_amdgcn_mfma_f32_32x32x16_bf16(af3[fm], bf3[fn], acc[fm][fn], 0, 0, 0); \
    __builtin_amdgcn_s_setprio(0);                                                    \
} while (0)

    // prologue: 2 K-tiles in flight (8 loads/thread each)
    STAGE_KT(0, 0);
    STAGE_KT(1, 1);

    // 4 K-tiles of BK=64; counted vmcnt keeps 1 tile ahead until drain
    GEMM_ITER(0, 0, "8", 1);
    GEMM_ITER(1, 1, "8", 1);
    GEMM_ITER(2, 0, "8", 0);
    GEMM_ITER(3, 1, "0", 0);

#undef GEMM_ITER
#undef STAGE_KT

    // ---- epilogue: label-free neg-part sum (3 VALU/elem) ----
    float lsum = 0.f;
#pragma unroll
    for (int fm = 0; fm < 4; ++fm)
#pragma unroll
        for (int fn = 0; fn < 2; ++fn)
#pragma unroll
            for (int r = 0; r < 16; ++r) {
                const float s = acc[fm][fn][r];
                lsum += (s > MARGINF) ? s : 0.0f;
            }
    // off-diag tiles x2 (symmetry); diag tiles: full sum == 2*upper + diag
    if (bi != bj) lsum *= 2.0f;

#pragma unroll
    for (int mask = 1; mask < 64; mask <<= 1) lsum += __shfl_xor(lsum, mask, 64);
    if (lane == 0) redbuf[wid] = lsum;
    __syncthreads();
    if (tid == 0) {
        float t = 0.f;
#pragma unroll
        for (int w = 0; w < 8; ++w) t += redbuf[w];
        partials[blockIdx.x] = (double)t;
    }
}

// ---------- pass 3: sparse same-label correction (coalesced, wave-per-pair) ----------
// One block (4 waves) per label. Each wave handles ordered pairs t = wid, wid+4, ...
// Lanes split the 256-dim dot: lane l loads 4 bf16 (8B) of each row -> coalesced.
__global__ void __launch_bounds__(256) samepair_k(const unsigned short* __restrict__ xb,
                                                  const int* __restrict__ tg,
                                                  double* __restrict__ partials2) {
    const int lbl = blockIdx.x;
    __shared__ int idx[128];
    __shared__ int cnt;
    __shared__ double dred[4];
    if (threadIdx.x == 0) cnt = 0;
    __syncthreads();
    for (int i = threadIdx.x; i < 8192; i += 256)
        if (tg[i] == lbl) { int q = atomicAdd(&cnt, 1); if (q < 128) idx[q] = i; }
    __syncthreads();
    int c = cnt; if (c > 128) c = 128;

    const int wid  = threadIdx.x >> 6;
    const int lane = threadIdx.x & 63;
    double dsum = 0.0;

    for (int t = wid; t < c * c; t += 4) {
        const int i = idx[t / c], j = idx[t % c];
        const ushort4* ri = (const ushort4*)(xb + (size_t)i * 256);
        const ushort4* rj = (const ushort4*)(xb + (size_t)j * 256);
        ushort4 a = ri[lane];
        ushort4 b = rj[lane];
        float s = bf2f(a.x) * bf2f(b.x);
        s = fmaf(bf2f(a.y), bf2f(b.y), s);
        s = fmaf(bf2f(a.z), bf2f(b.z), s);
        s = fmaf(bf2f(a.w), bf2f(b.w), s);
#pragma unroll
        for (int mask = 1; mask < 64; mask <<= 1) s += __shfl_xor(s, mask, 64);
        if (lane == 0) {
            const float posv = (s < 1.0f) ? (1.0f - s) : 0.0f;
            const float negv = (s > MARGINF) ? s : 0.0f;
            dsum += (double)(posv - negv);
        }
    }

    if (lane == 0) dred[wid] = dsum;
    __syncthreads();
    if (threadIdx.x == 0)
        partials2[lbl] = dred[0] + dred[1] + dred[2] + dred[3];
}

// ---------- pass 4: sum partials (528 gemm + 1000 sparse), divide by N ----------
__global__ void __launch_bounds__(256) finalize_k(const double* __restrict__ partials,
                                                  float* __restrict__ out) {
    double s = 0.0;
    for (int i = threadIdx.x; i < 1528; i += 256) s += partials[i];
#pragma unroll
    for (int mask = 1; mask < 64; mask <<= 1) s += __shfl_xor(s, mask, 64);
    __shared__ double red[4];
    const int wid = threadIdx.x >> 6;
    if ((threadIdx.x & 63) == 0) red[wid] = s;
    __syncthreads();
    if (threadIdx.x == 0)
        out[0] = (float)((red[0] + red[1] + red[2] + red[3]) / 8192.0);
}

extern "C" void kernel_launch(void* const* d_in, const int* in_sizes, int n_in,
                              void* d_out, int out_size, void* d_ws, size_t ws_size,
                              hipStream_t stream) {
    (void)in_sizes; (void)n_in; (void)out_size; (void)ws_size;
    const float* x  = (const float*)d_in[0];
    const int*   tg = (const int*)d_in[1];
    float* out = (float*)d_out;

    double* partials   = (double*)d_ws;                          // [0..527] gemm
    double* partials2  = (double*)d_ws + 528;                    // [528..1527] sparse
    unsigned short* xb = (unsigned short*)((char*)d_ws + 32768); // 4MB bf16 X (row-major)

    convert_k<<<1024, 256, 0, stream>>>(x, xb);
    gemm_loss_k<<<528, 512, 0, stream>>>(xb, partials);
    samepair_k<<<1000, 256, 0, stream>>>(xb, tg, partials2);
    finalize_k<<<1, 256, 0, stream>>>(partials, out);
}

// Round 9
// 112.161 us; speedup vs baseline: 1.1711x; 1.1711x over previous
//
#include <hip/hip_runtime.h>
#include <hip/hip_bf16.h>

// ContrastiveLoss: N=8192, D=256, NUM_IDS=1000, MARGIN=0.3
// R9: loss*N = sum_all negv(s)  [256^2-tile GEMM, label-free epilogue]
//           + sum_{same-label ordered pairs} [posv-negv]  [per-label 32x32 MFMA]
// GEMM: 1024 thr / 16 waves / 64x64 wave-tiles -> acc=64 VGPR (no spill at the
// 128-VGPR 4-wave/SIMD cap). Counted-vmcnt 2-buf pipeline (R6-verified).
// Sparse term: bin rows by label (global atomics), one wave per label does the
// whole pair block with 16 mfma_32x32x16 (no skew, no latency chains).

#define MARGINF 0.3f

typedef __attribute__((ext_vector_type(8))) short short8x;    // 8 bf16 (4 VGPRs)
typedef __attribute__((ext_vector_type(16))) float f32x16;    // 16 fp32 acc

__device__ __forceinline__ unsigned short f2bf(float f) {
    unsigned int u = __float_as_uint(f);
    unsigned int r = (u + 0x7fffu + ((u >> 16) & 1u)) >> 16;
    return (unsigned short)r;
}

// ---------- pass 1: fp32 -> bf16 row-major convert (verified R1-R8) ----------
__global__ void __launch_bounds__(256) convert_k(const float* __restrict__ x,
                                                 unsigned short* __restrict__ xb) {
    int i = blockIdx.x * 256 + threadIdx.x;          // 0 .. 262143
    const float4* p = reinterpret_cast<const float4*>(x) + (size_t)i * 2;
    float4 a = p[0];
    float4 b = p[1];
    short8x o;
    o[0] = (short)f2bf(a.x); o[1] = (short)f2bf(a.y);
    o[2] = (short)f2bf(a.z); o[3] = (short)f2bf(a.w);
    o[4] = (short)f2bf(b.x); o[5] = (short)f2bf(b.y);
    o[6] = (short)f2bf(b.z); o[7] = (short)f2bf(b.w);
    reinterpret_cast<short8x*>(xb)[i] = o;
}

// ---------- pass 2: 256^2 GEMM, 16 waves (4x4), label-free neg-sum ----------
// LDS: 2 bufs x (A 256x128B + B 256x128B) = 128KB. Swizzle (verified):
// LDS[row][c'] = global[row][c' ^ (row&7)], 16B chunks, on source + ds_read.
__global__ void __launch_bounds__(1024) gemm_loss_k(const unsigned short* __restrict__ xb,
                                                    double* __restrict__ partials) {
    // XCD-chunked swizzle (528 = 8*66, bijective)
    const int praw = blockIdx.x;
    const int p = (praw & 7) * 66 + (praw >> 3);
    // 1D upper-triangle decode on 32x32 tile grid: p -> (bi <= bj)
    int bi = (int)(32.5f - sqrtf(32.5f * 32.5f - 2.0f * (float)p));
    if (bi < 0) bi = 0;
    if (bi > 31) bi = 31;
    while (bi > 0 && (bi * (65 - bi)) / 2 > p) --bi;
    while (((bi + 1) * (64 - bi)) / 2 <= p) ++bi;
    const int bj = bi + (p - (bi * (65 - bi)) / 2);

    __shared__ __align__(16) char ldsb[2 * 65536];   // 128 KB
    __shared__ float redbuf[16];

    const int tid  = threadIdx.x;
    const int lane = tid & 63;
    const int wid  = tid >> 6;       // 0..15
    const int wr   = wid >> 2;       // 0..3 -> 64-row band
    const int wc   = wid & 3;        // 0..3 -> 64-col band

    const char* aBase = (const char*)(xb + (size_t)bi * 256 * 256);
    const char* bBase = (const char*)(xb + (size_t)bj * 256 * 256);

    // stage addressing: one issue = 1024 thr x 16B = 128 rows of 128B
    const int srow   = tid >> 3;                        // 0..127
    const int schunk = ((tid & 7) ^ (srow & 7)) << 4;   // swizzled source chunk

    // ds_read addressing
    const int l31 = lane & 31;
    const int hi  = lane >> 5;
    const int s7  = l31 & 7;
    int rA[2], rB[2], xc[4];
#pragma unroll
    for (int fm = 0; fm < 2; ++fm) rA[fm] = (wr * 64 + fm * 32 + l31) * 128;
#pragma unroll
    for (int fn = 0; fn < 2; ++fn) rB[fn] = 32768 + (wc * 64 + fn * 32 + l31) * 128;
#pragma unroll
    for (int ks = 0; ks < 4; ++ks) xc[ks] = (((2 * ks + hi) ^ s7) << 4);

    f32x16 acc00 = {}, acc01 = {}, acc10 = {}, acc11 = {};

#define STAGE_KT(BUF, T) do {                                                         \
    _Pragma("unroll")                                                                 \
    for (int is_ = 0; is_ < 2; ++is_) {                                               \
        const size_t gr_ = (size_t)(is_ * 128 + srow);                                \
        const char* sa_ = aBase + gr_ * 512 + (T) * 128 + schunk;                     \
        const char* sb_ = bBase + gr_ * 512 + (T) * 128 + schunk;                     \
        __builtin_amdgcn_global_load_lds(                                             \
            (const __attribute__((address_space(1))) unsigned int*)sa_,               \
            (__attribute__((address_space(3))) unsigned int*)(ldsb + (BUF) * 65536 + is_ * 16384 + tid * 16), \
            16, 0, 0);                                                                \
        __builtin_amdgcn_global_load_lds(                                             \
            (const __attribute__((address_space(1))) unsigned int*)sb_,               \
            (__attribute__((address_space(3))) unsigned int*)(ldsb + (BUF) * 65536 + 32768 + is_ * 16384 + tid * 16), \
            16, 0, 0);                                                                \
    }                                                                                 \
} while (0)

#define GEMM_ITER(T, BUF, VMSTR, DOSTAGE) do {                                        \
    asm volatile("s_waitcnt vmcnt(" VMSTR ")" ::: "memory");                          \
    __builtin_amdgcn_s_barrier();               /* KT T resident in BUF */            \
    const char* lb_ = ldsb + (BUF) * 65536;                                           \
    _Pragma("unroll")                                                                 \
    for (int ks = 0; ks < 3; ++ks) {                                                  \
        short8x a0 = *(const short8x*)(lb_ + rA[0] + xc[ks]);                         \
        short8x a1 = *(const short8x*)(lb_ + rA[1] + xc[ks]);                         \
        short8x b0 = *(const short8x*)(lb_ + rB[0] + xc[ks]);                         \
        short8x b1 = *(const short8x*)(lb_ + rB[1] + xc[ks]);                         \
        acc00 = __builtin_amdgcn_mfma_f32_32x32x16_bf16(a0, b0, acc00, 0, 0, 0);      \
        acc01 = __builtin_amdgcn_mfma_f32_32x32x16_bf16(a0, b1, acc01, 0, 0, 0);      \
        acc10 = __builtin_amdgcn_mfma_f32_32x32x16_bf16(a1, b0, acc10, 0, 0, 0);      \
        acc11 = __builtin_amdgcn_mfma_f32_32x32x16_bf16(a1, b1, acc11, 0, 0, 0);      \
    }                                                                                 \
    short8x a0l = *(const short8x*)(lb_ + rA[0] + xc[3]);                             \
    short8x a1l = *(const short8x*)(lb_ + rA[1] + xc[3]);                             \
    short8x b0l = *(const short8x*)(lb_ + rB[0] + xc[3]);                             \
    short8x b1l = *(const short8x*)(lb_ + rB[1] + xc[3]);                             \
    asm volatile("s_waitcnt lgkmcnt(0)" ::: "memory");                                \
    __builtin_amdgcn_sched_barrier(0);                                                \
    __builtin_amdgcn_s_barrier();               /* all waves done reading BUF */      \
    if (DOSTAGE) STAGE_KT(BUF, (T) + 2);        /* refill freed buffer */             \
    __builtin_amdgcn_s_setprio(1);                                                    \
    acc00 = __builtin_amdgcn_mfma_f32_32x32x16_bf16(a0l, b0l, acc00, 0, 0, 0);        \
    acc01 = __builtin_amdgcn_mfma_f32_32x32x16_bf16(a0l, b1l, acc01, 0, 0, 0);        \
    acc10 = __builtin_amdgcn_mfma_f32_32x32x16_bf16(a1l, b0l, acc10, 0, 0, 0);        \
    acc11 = __builtin_amdgcn_mfma_f32_32x32x16_bf16(a1l, b1l, acc11, 0, 0, 0);        \
    __builtin_amdgcn_s_setprio(0);                                                    \
} while (0)

    // prologue: 2 K-tiles in flight (4 loads/thread each)
    STAGE_KT(0, 0);
    STAGE_KT(1, 1);

    GEMM_ITER(0, 0, "4", 1);
    GEMM_ITER(1, 1, "4", 1);
    GEMM_ITER(2, 0, "4", 0);
    GEMM_ITER(3, 1, "0", 0);

#undef GEMM_ITER
#undef STAGE_KT

    // epilogue: label-free neg-part sum (verified R7/R8)
    float lsum = 0.f;
#pragma unroll
    for (int r = 0; r < 16; ++r) {
        float s;
        s = acc00[r]; lsum += (s > MARGINF) ? s : 0.0f;
        s = acc01[r]; lsum += (s > MARGINF) ? s : 0.0f;
        s = acc10[r]; lsum += (s > MARGINF) ? s : 0.0f;
        s = acc11[r]; lsum += (s > MARGINF) ? s : 0.0f;
    }
    if (bi != bj) lsum *= 2.0f;   // symmetry; diag tile = full sum

#pragma unroll
    for (int mask = 1; mask < 64; mask <<= 1) lsum += __shfl_xor(lsum, mask, 64);
    if (lane == 0) redbuf[wid] = lsum;
    __syncthreads();
    if (tid == 0) {
        float t = 0.f;
#pragma unroll
        for (int w = 0; w < 16; ++w) t += redbuf[w];
        partials[blockIdx.x] = (double)t;
    }
}

// ---------- pass 3a: zero label counters ----------
__global__ void __launch_bounds__(256) zero_k(int* __restrict__ gcnt) {
    int i = blockIdx.x * 256 + threadIdx.x;
    if (i < 1000) gcnt[i] = 0;
}

// ---------- pass 3b: bin row indices by label (global atomics) ----------
__global__ void __launch_bounds__(256) bin_k(const int* __restrict__ tg,
                                             int* __restrict__ gcnt,
                                             int* __restrict__ glist) {
    int i = blockIdx.x * 256 + threadIdx.x;   // 0..8191
    int l = tg[i];
    int q = atomicAdd(&gcnt[l], 1);
    if (q < 64) glist[l * 64 + q] = i;
}

// ---------- pass 3c: per-label pair block via 32x32 MFMA (skew-free) ----------
// One wave per label: gather <=32 rows' fragments, 16 mfma(af, af) gives the
// full 32x32 sim block; masked epilogue accumulates posv-negv over valid pairs
// (including i==j, which cancels term-1's diagonal negv).
__global__ void __launch_bounds__(256) pairsum_k(const unsigned short* __restrict__ xb,
                                                 const int* __restrict__ gcnt,
                                                 const int* __restrict__ glist,
                                                 double* __restrict__ partials2) {
    const int wid  = threadIdx.x >> 6;
    const int lane = threadIdx.x & 63;
    const int lbl  = blockIdx.x * 4 + wid;    // 250 blocks x 4 waves = 1000 labels
    const int l31  = lane & 31;
    const int hi   = lane >> 5;

    __shared__ double dred[4];

    const int c = gcnt[lbl];
    float lsum = 0.f;

    // quadrant (0,0): rows idx[0..31]
    {
        const int ridx = (l31 < c) ? glist[lbl * 64 + l31] : 0;
        const char* rp = (const char*)(xb + (size_t)ridx * 256);
        f32x16 acc = {};
#pragma unroll
        for (int ks = 0; ks < 16; ++ks) {
            short8x f = *(const short8x*)(rp + ks * 32 + hi * 16);
            acc = __builtin_amdgcn_mfma_f32_32x32x16_bf16(f, f, acc, 0, 0, 0);
        }
#pragma unroll
        for (int r = 0; r < 16; ++r) {
            const int row_l = (r & 3) + 8 * (r >> 2) + hi * 4;
            if (row_l < c && l31 < c) {
                const float s = acc[r];
                const float posv = (s < 1.0f) ? (1.0f - s) : 0.0f;
                const float negv = (s > MARGINF) ? s : 0.0f;
                lsum += posv - negv;
            }
        }
    }

    // rare path: labels with 32 < c <= 64 — remaining three quadrants
    if (c > 32) {
#pragma unroll 1
        for (int q = 1; q < 4; ++q) {
            const int qa = q >> 1, qb = q & 1;   // (0,1),(1,0),(1,1)
            const int ia = qa * 32 + l31, ib = qb * 32 + l31;
            const int ridxA = (ia < c) ? glist[lbl * 64 + ia] : 0;
            const int ridxB = (ib < c) ? glist[lbl * 64 + ib] : 0;
            const char* rpA = (const char*)(xb + (size_t)ridxA * 256);
            const char* rpB = (const char*)(xb + (size_t)ridxB * 256);
            f32x16 acc = {};
#pragma unroll
            for (int ks = 0; ks < 16; ++ks) {
                short8x fa = *(const short8x*)(rpA + ks * 32 + hi * 16);
                short8x fb = *(const short8x*)(rpB + ks * 32 + hi * 16);
                acc = __builtin_amdgcn_mfma_f32_32x32x16_bf16(fa, fb, acc, 0, 0, 0);
            }
#pragma unroll
            for (int r = 0; r < 16; ++r) {
                const int row_l = (r & 3) + 8 * (r >> 2) + hi * 4;
                if (qa * 32 + row_l < c && qb * 32 + l31 < c) {
                    const float s = acc[r];
                    const float posv = (s < 1.0f) ? (1.0f - s) : 0.0f;
                    const float negv = (s > MARGINF) ? s : 0.0f;
                    lsum += posv - negv;
                }
            }
        }
    }

    // wave reduce, then block reduce
#pragma unroll
    for (int mask = 1; mask < 64; mask <<= 1) lsum += __shfl_xor(lsum, mask, 64);
    if (lane == 0) dred[wid] = (double)lsum;
    __syncthreads();
    if (threadIdx.x == 0)
        partials2[blockIdx.x] = dred[0] + dred[1] + dred[2] + dred[3];
}

// ---------- pass 4: sum partials (528 gemm + 250 sparse), divide by N ----------
__global__ void __launch_bounds__(256) finalize_k(const double* __restrict__ partials,
                                                  float* __restrict__ out) {
    double s = 0.0;
    for (int i = threadIdx.x; i < 778; i += 256) s += partials[i];
#pragma unroll
    for (int mask = 1; mask < 64; mask <<= 1) s += __shfl_xor(s, mask, 64);
    __shared__ double red[4];
    const int wid = threadIdx.x >> 6;
    if ((threadIdx.x & 63) == 0) red[wid] = s;
    __syncthreads();
    if (threadIdx.x == 0)
        out[0] = (float)((red[0] + red[1] + red[2] + red[3]) / 8192.0);
}

extern "C" void kernel_launch(void* const* d_in, const int* in_sizes, int n_in,
                              void* d_out, int out_size, void* d_ws, size_t ws_size,
                              hipStream_t stream) {
    (void)in_sizes; (void)n_in; (void)out_size; (void)ws_size;
    const float* x  = (const float*)d_in[0];
    const int*   tg = (const int*)d_in[1];
    float* out = (float*)d_out;

    double* partials   = (double*)d_ws;                              // [0..527]
    double* partials2  = (double*)d_ws + 528;                        // [528..777]
    int*    gcnt       = (int*)((char*)d_ws + 8192);                 // 1000 ints
    int*    glist      = (int*)((char*)d_ws + 16384);                // 64000 ints (256KB)
    unsigned short* xb = (unsigned short*)((char*)d_ws + 294912);    // 4MB bf16 X

    convert_k<<<1024, 256, 0, stream>>>(x, xb);
    zero_k<<<4, 256, 0, stream>>>(gcnt);
    bin_k<<<32, 256, 0, stream>>>(tg, gcnt, glist);
    gemm_loss_k<<<528, 1024, 0, stream>>>(xb, partials);
    pairsum_k<<<250, 256, 0, stream>>>(xb, gcnt, glist, partials2);
    finalize_k<<<1, 256, 0, stream>>>(partials, out);
}

// Round 10
// 104.915 us; speedup vs baseline: 1.2520x; 1.0691x over previous
//
#include <hip/hip_runtime.h>
#include <hip/hip_bf16.h>

// ContrastiveLoss: N=8192, D=256, NUM_IDS=1000, MARGIN=0.3
// R10: loss*N = sum_all negv(s)  [LDS-free frag-major GEMM, 128x64 wave tiles]
//            + sum_{same-label ordered pairs} [posv-negv]  [per-label MFMA]
// GEMM: block = 256 rows x 128 cols of a 256^2 upper-tri supertile (x2 halves),
// 4 waves (2x2) of 128x64 -> F/B 42.7 (vs R5's 32). XCD-bijective swizzle
// (1056 = 8*132). Diag supertiles: full-sum weight 1 (2*upper+diag = full).

#define MARGINF 0.3f

typedef __attribute__((ext_vector_type(8))) short short8x;    // 8 bf16 (4 VGPRs)
typedef __attribute__((ext_vector_type(16))) float f32x16;    // 16 fp32 acc

__device__ __forceinline__ unsigned short f2bf(float f) {
    unsigned int u = __float_as_uint(f);
    unsigned int r = (u + 0x7fffu + ((u >> 16) & 1u)) >> 16;
    return (unsigned short)r;
}

// ---------- pass 1: fp32 -> bf16 fragment-major convert (verified R5) ----------
// Unit u (16B): lane = u&63, ks = (u>>6)&15, r32 = u>>10.
// Holds X[r32*32 + (lane&31)][ks*16 + (lane>>5)*8 .. +8] as 8 bf16.
// => fragment (r32, ks) contiguous: short8x index = (r32*16 + ks)*64 + lane.
__global__ void __launch_bounds__(256) convert_k(const float* __restrict__ x,
                                                 unsigned short* __restrict__ xb) {
    int u = blockIdx.x * 256 + threadIdx.x;          // 0 .. 262143
    int lane = u & 63;
    int ks   = (u >> 6) & 15;
    int r32  = u >> 10;
    int row  = r32 * 32 + (lane & 31);
    int col  = ks * 16 + (lane >> 5) * 8;
    const float4* src = reinterpret_cast<const float4*>(x + (size_t)row * 256 + col);
    float4 a = src[0];
    float4 b = src[1];
    short8x o;
    o[0] = (short)f2bf(a.x); o[1] = (short)f2bf(a.y);
    o[2] = (short)f2bf(a.z); o[3] = (short)f2bf(a.w);
    o[4] = (short)f2bf(b.x); o[5] = (short)f2bf(b.y);
    o[6] = (short)f2bf(b.z); o[7] = (short)f2bf(b.w);
    reinterpret_cast<short8x*>(xb)[u] = o;
}

// ---------- pass 2: LDS-free GEMM, 128x64 wave tiles, label-free neg-sum ----------
__global__ void __launch_bounds__(256, 2) gemm_loss_k(const unsigned short* __restrict__ xb,
                                                      double* __restrict__ partials) {
    // XCD-bijective swizzle: 1056 = 8 * 132
    const int praw  = blockIdx.x;
    const int p_lin = (praw & 7) * 132 + (praw >> 3);
    const int s     = p_lin >> 1;     // supertile 0..527
    const int h     = p_lin & 1;      // col half 0..1

    // 1D upper-triangle decode on 32x32 supertile grid: s -> (bi <= bj)
    int bi = (int)(32.5f - sqrtf(32.5f * 32.5f - 2.0f * (float)s));
    if (bi < 0) bi = 0;
    if (bi > 31) bi = 31;
    while (bi > 0 && (bi * (65 - bi)) / 2 > s) --bi;
    while (((bi + 1) * (64 - bi)) / 2 <= s) ++bi;
    const int bj = bi + (s - (bi * (65 - bi)) / 2);

    __shared__ float redbuf[4];

    const int tid  = threadIdx.x;
    const int lane = tid & 63;
    const int wid  = tid >> 6;       // 0..3
    const int wr   = wid >> 1;       // 0..1 -> 128-row band
    const int wc   = wid & 1;        // 0..1 -> 64-col band

    const short8x* xf = reinterpret_cast<const short8x*>(xb);
    // frag index: (r32*16 + ks)*64 + lane. A rows: bi*256+wr*128+fm*32;
    // B cols: bj*256 + h*128 + wc*64 + fn*32.
    const int aIdx = ((bi * 8 + wr * 4) * 16) * 64 + lane;           // + fm*1024 + ks*64
    const int bIdx = ((bj * 8 + h * 4 + wc * 2) * 16) * 64 + lane;   // + fn*1024 + ks*64

    f32x16 acc[4][2] = {};

    short8x a0 = xf[aIdx];
    short8x a1 = xf[aIdx + 1024];
    short8x a2 = xf[aIdx + 2048];
    short8x a3 = xf[aIdx + 3072];
    short8x b0 = xf[bIdx];
    short8x b1 = xf[bIdx + 1024];

#pragma unroll
    for (int ks = 0; ks < 16; ++ks) {
        short8x na0, na1, na2, na3, nb0, nb1;
        if (ks < 15) {
            const int o = (ks + 1) * 64;
            na0 = xf[aIdx + o];
            na1 = xf[aIdx + 1024 + o];
            na2 = xf[aIdx + 2048 + o];
            na3 = xf[aIdx + 3072 + o];
            nb0 = xf[bIdx + o];
            nb1 = xf[bIdx + 1024 + o];
        }
        acc[0][0] = __builtin_amdgcn_mfma_f32_32x32x16_bf16(a0, b0, acc[0][0], 0, 0, 0);
        acc[0][1] = __builtin_amdgcn_mfma_f32_32x32x16_bf16(a0, b1, acc[0][1], 0, 0, 0);
        acc[1][0] = __builtin_amdgcn_mfma_f32_32x32x16_bf16(a1, b0, acc[1][0], 0, 0, 0);
        acc[1][1] = __builtin_amdgcn_mfma_f32_32x32x16_bf16(a1, b1, acc[1][1], 0, 0, 0);
        acc[2][0] = __builtin_amdgcn_mfma_f32_32x32x16_bf16(a2, b0, acc[2][0], 0, 0, 0);
        acc[2][1] = __builtin_amdgcn_mfma_f32_32x32x16_bf16(a2, b1, acc[2][1], 0, 0, 0);
        acc[3][0] = __builtin_amdgcn_mfma_f32_32x32x16_bf16(a3, b0, acc[3][0], 0, 0, 0);
        acc[3][1] = __builtin_amdgcn_mfma_f32_32x32x16_bf16(a3, b1, acc[3][1], 0, 0, 0);
        if (ks < 15) { a0 = na0; a1 = na1; a2 = na2; a3 = na3; b0 = nb0; b1 = nb1; }
    }

    // epilogue: label-free neg-part sum (verified R7-R9 algebra)
    float lsum = 0.f;
#pragma unroll
    for (int fm = 0; fm < 4; ++fm)
#pragma unroll
        for (int fn = 0; fn < 2; ++fn)
#pragma unroll
            for (int r = 0; r < 16; ++r) {
                const float v = acc[fm][fn][r];
                lsum += (v > MARGINF) ? v : 0.0f;
            }
    if (bi != bj) lsum *= 2.0f;   // off-diag supertiles count twice; diag = full sum

#pragma unroll
    for (int mask = 1; mask < 64; mask <<= 1) lsum += __shfl_xor(lsum, mask, 64);
    if (lane == 0) redbuf[wid] = lsum;
    __syncthreads();
    if (tid == 0)
        partials[blockIdx.x] = (double)(redbuf[0] + redbuf[1] + redbuf[2] + redbuf[3]);
}

// ---------- pass 3a: zero label counters ----------
__global__ void __launch_bounds__(256) zero_k(int* __restrict__ gcnt) {
    int i = blockIdx.x * 256 + threadIdx.x;
    if (i < 1000) gcnt[i] = 0;
}

// ---------- pass 3b: bin row indices by label (global atomics) ----------
__global__ void __launch_bounds__(256) bin_k(const int* __restrict__ tg,
                                             int* __restrict__ gcnt,
                                             int* __restrict__ glist) {
    int i = blockIdx.x * 256 + threadIdx.x;   // 0..8191
    int l = tg[i];
    int q = atomicAdd(&gcnt[l], 1);
    if (q < 64) glist[l * 64 + q] = i;
}

// ---------- pass 3c: per-label pair block via 32x32 MFMA (verified R9) ----------
// Note: xb is fragment-major here; row i's ks-fragment 16B piece for lane-half hi
// lives at short8x index ((i>>5)*16 + ks)*64 + (hi<<5) + (i&31). For the gather
// we need row i's 8 bf16 at col ks*16 + hi*8 .. +8 -> that is exactly element
// lane' = hi*32 + (i&31) of fragment ((i>>5), ks).
__global__ void __launch_bounds__(256) pairsum_k(const unsigned short* __restrict__ xb,
                                                 const int* __restrict__ gcnt,
                                                 const int* __restrict__ glist,
                                                 double* __restrict__ partials2) {
    const int wid  = threadIdx.x >> 6;
    const int lane = threadIdx.x & 63;
    const int lbl  = blockIdx.x * 4 + wid;    // 250 blocks x 4 waves = 1000 labels
    const int l31  = lane & 31;
    const int hi   = lane >> 5;

    __shared__ double dred[4];

    int c = gcnt[lbl];
    if (c > 64) c = 64;
    float lsum = 0.f;

    const short8x* xf = reinterpret_cast<const short8x*>(xb);

    // quadrant (0,0): rows idx[0..31]
    {
        const int ridx = (l31 < c) ? glist[lbl * 64 + l31] : 0;
        const int fbase = (ridx >> 5) * 16;       // fragment r32 base
        const int fl    = hi * 32 + (ridx & 31);  // element within fragment
        f32x16 acc = {};
#pragma unroll
        for (int ks = 0; ks < 16; ++ks) {
            short8x f = xf[(fbase + ks) * 64 + fl];
            acc = __builtin_amdgcn_mfma_f32_32x32x16_bf16(f, f, acc, 0, 0, 0);
        }
#pragma unroll
        for (int r = 0; r < 16; ++r) {
            const int row_l = (r & 3) + 8 * (r >> 2) + hi * 4;
            if (row_l < c && l31 < c) {
                const float sv = acc[r];
                const float posv = (sv < 1.0f) ? (1.0f - sv) : 0.0f;
                const float negv = (sv > MARGINF) ? sv : 0.0f;
                lsum += posv - negv;
            }
        }
    }

    // rare path: labels with 32 < c <= 64 — remaining three quadrants
    if (c > 32) {
#pragma unroll 1
        for (int q = 1; q < 4; ++q) {
            const int qa = q >> 1, qb = q & 1;
            const int ia = qa * 32 + l31, ib = qb * 32 + l31;
            const int ridxA = (ia < c) ? glist[lbl * 64 + ia] : 0;
            const int ridxB = (ib < c) ? glist[lbl * 64 + ib] : 0;
            const int fbA = (ridxA >> 5) * 16, flA = hi * 32 + (ridxA & 31);
            const int fbB = (ridxB >> 5) * 16, flB = hi * 32 + (ridxB & 31);
            f32x16 acc = {};
#pragma unroll
            for (int ks = 0; ks < 16; ++ks) {
                short8x fa = xf[(fbA + ks) * 64 + flA];
                short8x fb = xf[(fbB + ks) * 64 + flB];
                acc = __builtin_amdgcn_mfma_f32_32x32x16_bf16(fa, fb, acc, 0, 0, 0);
            }
#pragma unroll
            for (int r = 0; r < 16; ++r) {
                const int row_l = (r & 3) + 8 * (r >> 2) + hi * 4;
                if (qa * 32 + row_l < c && qb * 32 + l31 < c) {
                    const float sv = acc[r];
                    const float posv = (sv < 1.0f) ? (1.0f - sv) : 0.0f;
                    const float negv = (sv > MARGINF) ? sv : 0.0f;
                    lsum += posv - negv;
                }
            }
        }
    }

#pragma unroll
    for (int mask = 1; mask < 64; mask <<= 1) lsum += __shfl_xor(lsum, mask, 64);
    if (lane == 0) dred[wid] = (double)lsum;
    __syncthreads();
    if (threadIdx.x == 0)
        partials2[blockIdx.x] = dred[0] + dred[1] + dred[2] + dred[3];
}

// ---------- pass 4: sum partials (1056 gemm + 250 sparse), divide by N ----------
__global__ void __launch_bounds__(256) finalize_k(const double* __restrict__ partials,
                                                  float* __restrict__ out) {
    double s = 0.0;
    for (int i = threadIdx.x; i < 1306; i += 256) s += partials[i];
#pragma unroll
    for (int mask = 1; mask < 64; mask <<= 1) s += __shfl_xor(s, mask, 64);
    __shared__ double red[4];
    const int wid = threadIdx.x >> 6;
    if ((threadIdx.x & 63) == 0) red[wid] = s;
    __syncthreads();
    if (threadIdx.x == 0)
        out[0] = (float)((red[0] + red[1] + red[2] + red[3]) / 8192.0);
}

extern "C" void kernel_launch(void* const* d_in, const int* in_sizes, int n_in,
                              void* d_out, int out_size, void* d_ws, size_t ws_size,
                              hipStream_t stream) {
    (void)in_sizes; (void)n_in; (void)out_size; (void)ws_size;
    const float* x  = (const float*)d_in[0];
    const int*   tg = (const int*)d_in[1];
    float* out = (float*)d_out;

    double* partials   = (double*)d_ws;                              // [0..1055]
    double* partials2  = (double*)d_ws + 1056;                       // [1056..1305]
    int*    gcnt       = (int*)((char*)d_ws + 12288);                // 1000 ints
    int*    glist      = (int*)((char*)d_ws + 16384);                // 64000 ints
    unsigned short* xb = (unsigned short*)((char*)d_ws + 294912);    // 4MB bf16 X (frag-major)

    convert_k<<<1024, 256, 0, stream>>>(x, xb);
    zero_k<<<4, 256, 0, stream>>>(gcnt);
    bin_k<<<32, 256, 0, stream>>>(tg, gcnt, glist);
    gemm_loss_k<<<1056, 256, 0, stream>>>(xb, partials);
    pairsum_k<<<250, 256, 0, stream>>>(xb, gcnt, glist, partials2);
    finalize_k<<<1, 256, 0, stream>>>(partials, out);
}